// Round 1
// baseline (24094.453 us; speedup 1.0000x reference)
//
#include <hip/hip_runtime.h>
#include <math.h>

// Problem constants
// V=10000, E=256, H=256, D=256, A=256, B=128, S=64
// 3H = 768, 2H = 512, feat = [h_new(256), w(512), e(256)] = 1024

__device__ __forceinline__ float dot4(const float4 a, const float4 b) {
    return fmaf(a.x, b.x, fmaf(a.y, b.y, fmaf(a.z, b.z, a.w * b.w)));
}

// ---------------------------------------------------------------------------
// emb[b,s,:] = emb_table[tok]*mask   (grid 8192, block 256)
__global__ void embed_kernel(const int* __restrict__ inp, const float* __restrict__ table,
                             float* __restrict__ emb) {
    int bs = blockIdx.x;
    int tok = inp[bs * 2];
    float msk = (float)inp[bs * 2 + 1];
    emb[bs * 256 + threadIdx.x] = table[tok * 256 + threadIdx.x] * msk;
}

// ---------------------------------------------------------------------------
// One encoder time-step, both directions (blockIdx.y = dir).
// blockIdx.x: bits 0..2 = d-tile (8 x 32), bits 3..6 = b-tile (16 x 8)
__global__ __launch_bounds__(256) void enc_step_kernel(
    const float* __restrict__ emb,
    const float* __restrict__ Wih_f, const float* __restrict__ Whh_f,
    const float* __restrict__ bih_f, const float* __restrict__ bhh_f,
    const float* __restrict__ Wih_b, const float* __restrict__ Whh_b,
    const float* __restrict__ bih_b, const float* __restrict__ bhh_b,
    const float* __restrict__ hin_f, float* __restrict__ hout_f,
    const float* __restrict__ hin_b, float* __restrict__ hout_b,
    float* __restrict__ enc_out, int step)
{
    const int dir = blockIdx.y;
    const float* Wih = dir ? Wih_b : Wih_f;
    const float* Whh = dir ? Whh_b : Whh_f;
    const float* bih = dir ? bih_b : bih_f;
    const float* bhh = dir ? bhh_b : bhh_f;
    const float* hin = dir ? hin_b : hin_f;
    float* hout = dir ? hout_b : hout_f;
    const int t = dir ? (63 - step) : step;

    const int tid = threadIdx.x;
    const int dl = tid & 31;
    const int bsub = tid >> 5;                 // 0..7
    const int d0 = (blockIdx.x & 7) * 32;
    const int b0 = (blockIdx.x >> 3) * 8;
    const int d = d0 + dl;
    const int b = b0 + bsub;

    __shared__ float xs[8][256];
    __shared__ float hs[8][256];
    for (int i = tid; i < 2048; i += 256) {
        int bl = i >> 8, e = i & 255;
        int bb = b0 + bl;
        xs[bl][e] = emb[(bb * 64 + t) * 256 + e];
        hs[bl][e] = hin[bb * 256 + e];
    }
    __syncthreads();

    const float4* x4 = (const float4*)xs[bsub];
    const float4* h4 = (const float4*)hs[bsub];
    const float4* wr_i = (const float4*)(Wih + (size_t)d * 256);
    const float4* wz_i = (const float4*)(Wih + (size_t)(256 + d) * 256);
    const float4* wn_i = (const float4*)(Wih + (size_t)(512 + d) * 256);
    const float4* wr_h = (const float4*)(Whh + (size_t)d * 256);
    const float4* wz_h = (const float4*)(Whh + (size_t)(256 + d) * 256);
    const float4* wn_h = (const float4*)(Whh + (size_t)(512 + d) * 256);

    float rs = 0.f, zs = 0.f, nx = 0.f, nh = 0.f;
    for (int k = 0; k < 64; ++k) {
        float4 xv = x4[k];
        float4 hv = h4[k];
        rs += dot4(xv, wr_i[k]) + dot4(hv, wr_h[k]);
        zs += dot4(xv, wz_i[k]) + dot4(hv, wz_h[k]);
        nx += dot4(xv, wn_i[k]);
        nh += dot4(hv, wn_h[k]);
    }
    rs += bih[d] + bhh[d];
    zs += bih[256 + d] + bhh[256 + d];
    nx += bih[512 + d];
    nh += bhh[512 + d];

    float r = 1.0f / (1.0f + expf(-rs));
    float z = 1.0f / (1.0f + expf(-zs));
    float n = tanhf(nx + r * nh);
    float hprev = hs[bsub][d];
    float hn = (1.0f - z) * n + z * hprev;

    hout[b * 256 + d] = hn;
    enc_out[(b * 64 + t) * 512 + dir * 256 + d] = hn;
}

// ---------------------------------------------------------------------------
// hidden = tanh([f_h, b_h] @ enc_fc_W.T + b)   (grid 128, block 256)
__global__ __launch_bounds__(256) void enc_fc_kernel(
    const float* __restrict__ hf, const float* __restrict__ hb,
    const float* __restrict__ W, const float* __restrict__ bias,
    float* __restrict__ hdec0)
{
    int b = blockIdx.x, tid = threadIdx.x;
    __shared__ float xs[512];
    xs[tid] = hf[b * 256 + tid];
    xs[256 + tid] = hb[b * 256 + tid];
    __syncthreads();
    const float4* w4 = (const float4*)(W + (size_t)tid * 512);
    const float4* x4 = (const float4*)xs;
    float s = 0.f;
    for (int k = 0; k < 128; ++k) s += dot4(x4[k], w4[k]);
    hdec0[b * 256 + tid] = tanhf(s + bias[tid]);
}

// ---------------------------------------------------------------------------
// Generic C[M,N] = A[M,K] @ W[N,K]^T + bias.  64x64 tile, 4x4 micro-tile.
// Interleaved row mapping (tb+16i) keeps LDS reads at <=2-way bank aliasing.
#define GPAD 36
__global__ __launch_bounds__(256) void gemm_bias_kernel(
    const float* __restrict__ Amat, int lda,
    const float* __restrict__ Wmat, int ldw,
    const float* __restrict__ bias,
    float* __restrict__ C, long ldc,
    int M, int N, int K)
{
    const int tid = threadIdx.x;
    const int tb = tid & 15, tv = tid >> 4;
    const int m0 = blockIdx.y * 64, n0 = blockIdx.x * 64;
    __shared__ float As[64][GPAD];
    __shared__ float Ws[64][GPAD];
    float acc[4][4] = {};

    for (int k0 = 0; k0 < K; k0 += 32) {
        for (int i = tid; i < 2048; i += 256) {
            int r = i >> 5, kk = i & 31;
            int m = m0 + r;
            As[r][kk] = (m < M) ? Amat[(long)m * lda + k0 + kk] : 0.f;
            int n = n0 + r;
            Ws[r][kk] = (n < N) ? Wmat[(long)n * ldw + k0 + kk] : 0.f;
        }
        __syncthreads();
        for (int kk = 0; kk < 32; kk += 4) {
            float4 av[4], wv[4];
#pragma unroll
            for (int i = 0; i < 4; ++i) av[i] = *(const float4*)&As[tb + 16 * i][kk];
#pragma unroll
            for (int j = 0; j < 4; ++j) wv[j] = *(const float4*)&Ws[tv + 16 * j][kk];
#pragma unroll
            for (int i = 0; i < 4; ++i)
#pragma unroll
                for (int j = 0; j < 4; ++j)
                    acc[i][j] += dot4(av[i], wv[j]);
        }
        __syncthreads();
    }

#pragma unroll
    for (int i = 0; i < 4; ++i) {
        int m = m0 + tb + 16 * i;
        if (m >= M) continue;
#pragma unroll
        for (int j = 0; j < 4; ++j) {
            int n = n0 + tv + 16 * j;
            if (n >= N) continue;
            C[(long)m * ldc + n] = acc[i][j] + bias[n];
        }
    }
}

// ---------------------------------------------------------------------------
// Attention for one decoder step. Block per b.
// hE[a] = sum_d h[d]*attn_W[a,d];  score[s] = sum_a tanh(hE[a] + enc_att[b,s,a])
// a = softmax_s(score); w[j] = sum_s a_s * enc_out[b,s,j]  -> feat[b,256:768]
__global__ __launch_bounds__(256) void attn_kernel(
    const float* __restrict__ hprev, const float* __restrict__ attn_W,
    const float* __restrict__ enc_att, const float* __restrict__ enc_out,
    float* __restrict__ feat)
{
    const int b = blockIdx.x, tid = threadIdx.x;
    __shared__ float hsh[256];
    __shared__ float hE[256];
    __shared__ float part[256];
    __shared__ float aw[64];

    hsh[tid] = hprev[b * 256 + tid];
    __syncthreads();
    {
        const float4* w4 = (const float4*)(attn_W + (size_t)tid * 768);
        const float4* h4 = (const float4*)hsh;
        float s = 0.f;
        for (int k = 0; k < 64; ++k) s += dot4(h4[k], w4[k]);
        hE[tid] = s;
    }
    __syncthreads();
    {
        const int si = tid & 63, g = tid >> 6;
        const float* ea = enc_att + ((size_t)b * 64 + si) * 256 + g * 64;
        const float* he = hE + g * 64;
        float p = 0.f;
        for (int a = 0; a < 64; ++a) p += tanhf(he[a] + ea[a]);
        part[tid] = p;
    }
    __syncthreads();
    if (tid < 64) {
        float sc = part[tid] + part[64 + tid] + part[128 + tid] + part[192 + tid];
        float m = sc;
        for (int off = 32; off; off >>= 1) m = fmaxf(m, __shfl_xor(m, off));
        float ex = expf(sc - m);
        float sum = ex;
        for (int off = 32; off; off >>= 1) sum += __shfl_xor(sum, off);
        aw[tid] = ex / sum;
    }
    __syncthreads();
    {
        float w0 = 0.f, w1 = 0.f;
        for (int s2 = 0; s2 < 64; ++s2) {
            float as = aw[s2];
            const float* eo = enc_out + ((size_t)b * 64 + s2) * 512;
            w0 = fmaf(as, eo[tid], w0);
            w1 = fmaf(as, eo[256 + tid], w1);
        }
        feat[b * 1024 + 256 + tid] = w0;
        feat[b * 1024 + 512 + tid] = w1;
    }
}

// ---------------------------------------------------------------------------
// Decoder GRU step: h_new[b,d]. rnn_in = [e(256), w(512)] from feat; h from hin.
// Writes hout and feat[b,0:256].
__global__ __launch_bounds__(256) void dec_gru_kernel(
    const float* __restrict__ feat, const float* __restrict__ hin,
    const float* __restrict__ Wih, const float* __restrict__ Whh,
    const float* __restrict__ bih, const float* __restrict__ bhh,
    float* __restrict__ hout, float* __restrict__ feat_h)
{
    const int tid = threadIdx.x;
    const int dl = tid & 31, bsub = tid >> 5;
    const int d0 = (blockIdx.x & 7) * 32, b0 = (blockIdx.x >> 3) * 8;
    const int d = d0 + dl, b = b0 + bsub;

    __shared__ float rin[8][768];
    __shared__ float hsh[8][256];
    for (int i = tid; i < 2048; i += 256) {           // e -> rin[:,0:256]
        int bl = i >> 8, k = i & 255;
        rin[bl][k] = feat[(b0 + bl) * 1024 + 768 + k];
    }
    for (int i = tid; i < 4096; i += 256) {           // w -> rin[:,256:768]
        int bl = i >> 9, k = i & 511;
        rin[bl][256 + k] = feat[(b0 + bl) * 1024 + 256 + k];
    }
    for (int i = tid; i < 2048; i += 256) {
        int bl = i >> 8, k = i & 255;
        hsh[bl][k] = hin[(b0 + bl) * 256 + k];
    }
    __syncthreads();

    const float4* xv4 = (const float4*)rin[bsub];
    const float4* hv4 = (const float4*)hsh[bsub];
    const float4* Wr = (const float4*)(Wih + (size_t)d * 768);
    const float4* Wz = (const float4*)(Wih + (size_t)(256 + d) * 768);
    const float4* Wn = (const float4*)(Wih + (size_t)(512 + d) * 768);
    const float4* Ur = (const float4*)(Whh + (size_t)d * 256);
    const float4* Uz = (const float4*)(Whh + (size_t)(256 + d) * 256);
    const float4* Un = (const float4*)(Whh + (size_t)(512 + d) * 256);

    float rs = 0.f, zs = 0.f, nx = 0.f, nh = 0.f;
    for (int k = 0; k < 192; ++k) {
        float4 xv = xv4[k];
        rs += dot4(xv, Wr[k]);
        zs += dot4(xv, Wz[k]);
        nx += dot4(xv, Wn[k]);
    }
    for (int k = 0; k < 64; ++k) {
        float4 hv = hv4[k];
        rs += dot4(hv, Ur[k]);
        zs += dot4(hv, Uz[k]);
        nh += dot4(hv, Un[k]);
    }
    rs += bih[d] + bhh[d];
    zs += bih[256 + d] + bhh[256 + d];
    nx += bih[512 + d];
    nh += bhh[512 + d];

    float r = 1.0f / (1.0f + expf(-rs));
    float z = 1.0f / (1.0f + expf(-zs));
    float n = tanhf(nx + r * nh);
    float hprev = hsh[bsub][d];
    float hn = (1.0f - z) * n + z * hprev;

    hout[b * 256 + d] = hn;
    feat_h[b * 1024 + d] = hn;
}

// ---------------------------------------------------------------------------
// Argmax (first-max semantics, matching jnp.argmax) + next-token embedding.
// Block per b; logits base = d_out + t*10000, row stride 640000.
__global__ __launch_bounds__(256) void argmax_kernel(
    const float* __restrict__ logits, const float* __restrict__ table,
    int* __restrict__ tok, float* __restrict__ feat)
{
    const int b = blockIdx.x, tid = threadIdx.x;
    const float* row = logits + (long)b * 640000;
    float best = -3.402823466e38f;
    int bi = 0;
    for (int v = tid; v < 10000; v += 256) {
        float x = row[v];
        if (x > best) { best = x; bi = v; }     // per-thread ascending -> first max
    }
    __shared__ float bv[256];
    __shared__ int bix[256];
    bv[tid] = best; bix[tid] = bi;
    __syncthreads();
    for (int s2 = 128; s2; s2 >>= 1) {
        if (tid < s2) {
            float o = bv[tid + s2]; int oi = bix[tid + s2];
            if (o > bv[tid] || (o == bv[tid] && oi < bix[tid])) { bv[tid] = o; bix[tid] = oi; }
        }
        __syncthreads();
    }
    int t0 = bix[0];
    if (tid == 0) tok[b] = t0;
    feat[b * 1024 + 768 + tid] = table[(size_t)t0 * 256 + tid];
}

// ---------------------------------------------------------------------------
// feat e-part init with tok0 = 0
__global__ void init_e_kernel(const float* __restrict__ table, float* __restrict__ feat) {
    feat[blockIdx.x * 1024 + 768 + threadIdx.x] = table[threadIdx.x];
}

// ---------------------------------------------------------------------------
// In-place log_softmax over each row of d_out (8192 x 10000).
// Rows with (row % 64)==0 are the one-hot "first" rows -> write closed form.
__global__ __launch_bounds__(256) void logsoftmax_kernel(float* __restrict__ out) {
    const int row = blockIdx.x;
    float* p = out + (long)row * 10000;
    const int tid = threadIdx.x;
    __shared__ float red[256];

    if ((row & 63) == 0) {
        float lse = logf(expf(1.0f) + 9999.0f);
        for (int v = tid; v < 10000; v += 256) p[v] = (v == 0 ? 1.0f : 0.0f) - lse;
        return;
    }

    float vals[40];
    float m = -3.402823466e38f;
#pragma unroll
    for (int i = 0; i < 40; ++i) {
        int v = tid + (i << 8);
        vals[i] = (v < 10000) ? p[v] : -3.402823466e38f;
        m = fmaxf(m, vals[i]);
    }
    red[tid] = m; __syncthreads();
    for (int s2 = 128; s2; s2 >>= 1) { if (tid < s2) red[tid] = fmaxf(red[tid], red[tid + s2]); __syncthreads(); }
    m = red[0]; __syncthreads();

    float sum = 0.f;
#pragma unroll
    for (int i = 0; i < 40; ++i) {
        int v = tid + (i << 8);
        if (v < 10000) sum += expf(vals[i] - m);
    }
    red[tid] = sum; __syncthreads();
    for (int s2 = 128; s2; s2 >>= 1) { if (tid < s2) red[tid] += red[tid + s2]; __syncthreads(); }
    float lse = m + logf(red[0]);

#pragma unroll
    for (int i = 0; i < 40; ++i) {
        int v = tid + (i << 8);
        if (v < 10000) p[v] = vals[i] - lse;
    }
}

// ---------------------------------------------------------------------------
extern "C" void kernel_launch(void* const* d_in, const int* in_sizes, int n_in,
                              void* d_out, int out_size, void* d_ws, size_t ws_size,
                              hipStream_t stream)
{
    const int*   inp      = (const int*)d_in[0];
    const float* emb_tab  = (const float*)d_in[1];
    const float* eWih_f   = (const float*)d_in[2];
    const float* eWhh_f   = (const float*)d_in[3];
    const float* ebih_f   = (const float*)d_in[4];
    const float* ebhh_f   = (const float*)d_in[5];
    const float* eWih_b   = (const float*)d_in[6];
    const float* eWhh_b   = (const float*)d_in[7];
    const float* ebih_b   = (const float*)d_in[8];
    const float* ebhh_b   = (const float*)d_in[9];
    const float* fc_W     = (const float*)d_in[10];
    const float* fc_b     = (const float*)d_in[11];
    const float* attn_W   = (const float*)d_in[12];
    const float* attn_b   = (const float*)d_in[13];
    const float* dWih     = (const float*)d_in[14];
    const float* dWhh     = (const float*)d_in[15];
    const float* dbih     = (const float*)d_in[16];
    const float* dbhh     = (const float*)d_in[17];
    const float* out_W    = (const float*)d_in[18];
    const float* out_b    = (const float*)d_in[19];

    float* ws = (float*)d_ws;
    float* emb     = ws;                    // 2,097,152  (B*S*E)
    float* enc_out = emb + 2097152;         // 4,194,304  (B*S*512)
    float* enc_att = enc_out + 4194304;     // 2,097,152  (B*S*256)
    float* hf      = enc_att + 2097152;     // 2 * 32768
    float* hb      = hf + 65536;            // 2 * 32768
    float* hdec    = hb + 65536;            // 2 * 32768
    float* feat    = hdec + 65536;          // 131,072    (B*1024)
    int*   tok     = (int*)(feat + 131072); // 128
    float* out     = (float*)d_out;

    // ---- encoder ----
    embed_kernel<<<8192, 256, 0, stream>>>(inp, emb_tab, emb);
    hipMemsetAsync(hf, 0, 32768 * sizeof(float), stream);
    hipMemsetAsync(hb, 0, 32768 * sizeof(float), stream);
    for (int i = 0; i < 64; ++i) {
        const float* hinf = hf + (i & 1) * 32768;
        float* houtf = hf + ((i + 1) & 1) * 32768;
        const float* hinb = hb + (i & 1) * 32768;
        float* houtb = hb + ((i + 1) & 1) * 32768;
        enc_step_kernel<<<dim3(128, 2), 256, 0, stream>>>(
            emb, eWih_f, eWhh_f, ebih_f, ebhh_f, eWih_b, eWhh_b, ebih_b, ebhh_b,
            hinf, houtf, hinb, houtb, enc_out, i);
    }
    // final states are in buffer 0 of each ping-pong pair
    enc_fc_kernel<<<128, 256, 0, stream>>>(hf, hb, fc_W, fc_b, hdec);

    // precompute enc_att[b,s,a] = enc_out @ attn_W[:,256:768].T + attn_b
    gemm_bias_kernel<<<dim3(4, 128), 256, 0, stream>>>(
        enc_out, 512, attn_W + 256, 768, attn_b, enc_att, 256, 8192, 256, 512);

    init_e_kernel<<<128, 256, 0, stream>>>(emb_tab, feat);

    // ---- decoder ----
    for (int t = 1; t < 64; ++t) {
        const float* hprev = hdec + ((t - 1) & 1) * 32768;
        float* hcur = hdec + (t & 1) * 32768;
        attn_kernel<<<128, 256, 0, stream>>>(hprev, attn_W, enc_att, enc_out, feat);
        dec_gru_kernel<<<128, 256, 0, stream>>>(feat, hprev, dWih, dWhh, dbih, dbhh, hcur, feat);
        gemm_bias_kernel<<<dim3(157, 2), 256, 0, stream>>>(
            feat, 1024, out_W, 1024, out_b, out + (long)t * 10000, 640000, 128, 10000, 1024);
        if (t < 63)
            argmax_kernel<<<128, 256, 0, stream>>>(out + (long)t * 10000, emb_tab, tok, feat);
    }

    // ---- final log_softmax (also writes the t=0 one-hot rows) ----
    logsoftmax_kernel<<<8192, 256, 0, stream>>>(out);
}

// Round 2
// 19996.770 us; speedup vs baseline: 1.2049x; 1.2049x over previous
//
#include <hip/hip_runtime.h>
#include <math.h>

// Problem constants
// V=10000, E=256, H=256, D=256, A=256, B=128, S=64
// 3H = 768, 2H = 512, feat = [h_new(256), w(512), e(256)] = 1024

__device__ __forceinline__ float dot4(const float4 a, const float4 b) {
    return fmaf(a.x, b.x, fmaf(a.y, b.y, fmaf(a.z, b.z, a.w * b.w)));
}

// ---------------------------------------------------------------------------
// emb[b,s,:] = emb_table[tok]*mask   (grid 8192, block 256)
__global__ void embed_kernel(const int* __restrict__ inp, const float* __restrict__ table,
                             float* __restrict__ emb) {
    int bs = blockIdx.x;
    int tok = inp[bs * 2];
    float msk = (float)inp[bs * 2 + 1];
    emb[bs * 256 + threadIdx.x] = table[tok * 256 + threadIdx.x] * msk;
}

// ---------------------------------------------------------------------------
// One encoder time-step, both directions (blockIdx.y = dir).
__global__ __launch_bounds__(256) void enc_step_kernel(
    const float* __restrict__ emb,
    const float* __restrict__ Wih_f, const float* __restrict__ Whh_f,
    const float* __restrict__ bih_f, const float* __restrict__ bhh_f,
    const float* __restrict__ Wih_b, const float* __restrict__ Whh_b,
    const float* __restrict__ bih_b, const float* __restrict__ bhh_b,
    const float* __restrict__ hin_f, float* __restrict__ hout_f,
    const float* __restrict__ hin_b, float* __restrict__ hout_b,
    float* __restrict__ enc_out, int step)
{
    const int dir = blockIdx.y;
    const float* Wih = dir ? Wih_b : Wih_f;
    const float* Whh = dir ? Whh_b : Whh_f;
    const float* bih = dir ? bih_b : bih_f;
    const float* bhh = dir ? bhh_b : bhh_f;
    const float* hin = dir ? hin_b : hin_f;
    float* hout = dir ? hout_b : hout_f;
    const int t = dir ? (63 - step) : step;

    const int tid = threadIdx.x;
    const int dl = tid & 31;
    const int bsub = tid >> 5;                 // 0..7
    const int d0 = (blockIdx.x & 7) * 32;
    const int b0 = (blockIdx.x >> 3) * 8;
    const int d = d0 + dl;
    const int b = b0 + bsub;

    __shared__ float xs[8][256];
    __shared__ float hs[8][256];
    for (int i = tid; i < 2048; i += 256) {
        int bl = i >> 8, e = i & 255;
        int bb = b0 + bl;
        xs[bl][e] = emb[(bb * 64 + t) * 256 + e];
        hs[bl][e] = hin[bb * 256 + e];
    }
    __syncthreads();

    const float4* x4 = (const float4*)xs[bsub];
    const float4* h4 = (const float4*)hs[bsub];
    const float4* wr_i = (const float4*)(Wih + (size_t)d * 256);
    const float4* wz_i = (const float4*)(Wih + (size_t)(256 + d) * 256);
    const float4* wn_i = (const float4*)(Wih + (size_t)(512 + d) * 256);
    const float4* wr_h = (const float4*)(Whh + (size_t)d * 256);
    const float4* wz_h = (const float4*)(Whh + (size_t)(256 + d) * 256);
    const float4* wn_h = (const float4*)(Whh + (size_t)(512 + d) * 256);

    float rs = 0.f, zs = 0.f, nx = 0.f, nh = 0.f;
    for (int k = 0; k < 64; ++k) {
        float4 xv = x4[k];
        float4 hv = h4[k];
        rs += dot4(xv, wr_i[k]) + dot4(hv, wr_h[k]);
        zs += dot4(xv, wz_i[k]) + dot4(hv, wz_h[k]);
        nx += dot4(xv, wn_i[k]);
        nh += dot4(hv, wn_h[k]);
    }
    rs += bih[d] + bhh[d];
    zs += bih[256 + d] + bhh[256 + d];
    nx += bih[512 + d];
    nh += bhh[512 + d];

    float r = 1.0f / (1.0f + expf(-rs));
    float z = 1.0f / (1.0f + expf(-zs));
    float n = tanhf(nx + r * nh);
    float hprev = hs[bsub][d];
    float hn = (1.0f - z) * n + z * hprev;

    hout[b * 256 + d] = hn;
    enc_out[(b * 64 + t) * 512 + dir * 256 + d] = hn;
}

// ---------------------------------------------------------------------------
// hidden = tanh([f_h, b_h] @ enc_fc_W.T + b)   (grid 128, block 256)
__global__ __launch_bounds__(256) void enc_fc_kernel(
    const float* __restrict__ hf, const float* __restrict__ hb,
    const float* __restrict__ W, const float* __restrict__ bias,
    float* __restrict__ hdec0)
{
    int b = blockIdx.x, tid = threadIdx.x;
    __shared__ float xs[512];
    xs[tid] = hf[b * 256 + tid];
    xs[256 + tid] = hb[b * 256 + tid];
    __syncthreads();
    const float4* w4 = (const float4*)(W + (size_t)tid * 512);
    const float4* x4 = (const float4*)xs;
    float s = 0.f;
    for (int k = 0; k < 128; ++k) s += dot4(x4[k], w4[k]);
    hdec0[b * 256 + tid] = tanhf(s + bias[tid]);
}

// ---------------------------------------------------------------------------
// C[M,N] = A[M,K] @ W[N,K]^T + bias.  64x64 tile, 4x4 micro-tile, BK=64,
// register-double-buffered staging with float4 loads. M,K multiples of 64.
// K-accumulation order identical to round-1 kernel (bit-identical logits).
#define GP 68
__global__ __launch_bounds__(256) void gemm2_kernel(
    const float* __restrict__ Amat, int lda,
    const float* __restrict__ Wmat, int ldw,
    const float* __restrict__ bias,
    float* __restrict__ C, long ldc,
    int N, int K)
{
    const int tid = threadIdx.x;
    const int tn = tid & 15;        // output col group (coalesced stores)
    const int tm = tid >> 4;        // output row group
    const long m0 = (long)blockIdx.y * 64;
    const int n0 = blockIdx.x * 64;
    __shared__ float As[64][GP];
    __shared__ float Ws[64][GP];

    // staging: thread loads rows tm+16q, cols [tn*4, tn*4+4) of each 64x64 chunk
    const float* Abase = Amat + (m0 + tm) * lda + tn * 4;
    float4 ar[4], wr[4];
    float acc[4][4] = {};

    {
        // k0 = 0 prologue
#pragma unroll
        for (int q = 0; q < 4; ++q)
            ar[q] = *(const float4*)(Abase + (long)16 * q * lda);
#pragma unroll
        for (int q = 0; q < 4; ++q) {
            int n = n0 + tm + 16 * q;
            wr[q] = (n < N) ? *(const float4*)(Wmat + (long)n * ldw + tn * 4)
                            : make_float4(0.f, 0.f, 0.f, 0.f);
        }
    }

    int k0 = 0;
    while (true) {
#pragma unroll
        for (int q = 0; q < 4; ++q) {
            *(float4*)&As[tm + 16 * q][tn * 4] = ar[q];
            *(float4*)&Ws[tm + 16 * q][tn * 4] = wr[q];
        }
        __syncthreads();

        const int kn = k0 + 64;
        if (kn < K) {
#pragma unroll
            for (int q = 0; q < 4; ++q)
                ar[q] = *(const float4*)(Abase + (long)16 * q * lda + kn);
#pragma unroll
            for (int q = 0; q < 4; ++q) {
                int n = n0 + tm + 16 * q;
                wr[q] = (n < N) ? *(const float4*)(Wmat + (long)n * ldw + tn * 4 + kn)
                                : make_float4(0.f, 0.f, 0.f, 0.f);
            }
        }

#pragma unroll
        for (int kk = 0; kk < 64; kk += 4) {
            float4 av[4], wv[4];
#pragma unroll
            for (int i = 0; i < 4; ++i) av[i] = *(const float4*)&As[tm + 16 * i][kk];
#pragma unroll
            for (int j = 0; j < 4; ++j) wv[j] = *(const float4*)&Ws[tn + 16 * j][kk];
#pragma unroll
            for (int i = 0; i < 4; ++i)
#pragma unroll
                for (int j = 0; j < 4; ++j)
                    acc[i][j] += dot4(av[i], wv[j]);
        }

        if (kn >= K) break;
        __syncthreads();
        k0 = kn;
    }

#pragma unroll
    for (int i = 0; i < 4; ++i) {
        long m = m0 + tm + 16 * i;
#pragma unroll
        for (int j = 0; j < 4; ++j) {
            int n = n0 + tn + 16 * j;
            if (n < N) C[m * ldc + n] = acc[i][j] + bias[n];
        }
    }
}

// ---------------------------------------------------------------------------
// Attention for one decoder step. Block per b.
__global__ __launch_bounds__(256) void attn_kernel(
    const float* __restrict__ hprev, const float* __restrict__ attn_W,
    const float* __restrict__ enc_att, const float* __restrict__ enc_out,
    float* __restrict__ feat)
{
    const int b = blockIdx.x, tid = threadIdx.x;
    __shared__ float hsh[256];
    __shared__ float hE[256];
    __shared__ float part[256];
    __shared__ float aw[64];

    hsh[tid] = hprev[b * 256 + tid];
    __syncthreads();
    {
        const float4* w4 = (const float4*)(attn_W + (size_t)tid * 768);
        const float4* h4 = (const float4*)hsh;
        float s = 0.f;
        for (int k = 0; k < 64; ++k) s += dot4(h4[k], w4[k]);
        hE[tid] = s;
    }
    __syncthreads();
    {
        const int si = tid & 63, g = tid >> 6;
        const float* ea = enc_att + ((size_t)b * 64 + si) * 256 + g * 64;
        const float* he = hE + g * 64;
        float p = 0.f;
        for (int a = 0; a < 64; ++a) p += tanhf(he[a] + ea[a]);
        part[tid] = p;
    }
    __syncthreads();
    if (tid < 64) {
        float sc = part[tid] + part[64 + tid] + part[128 + tid] + part[192 + tid];
        float m = sc;
        for (int off = 32; off; off >>= 1) m = fmaxf(m, __shfl_xor(m, off));
        float ex = expf(sc - m);
        float sum = ex;
        for (int off = 32; off; off >>= 1) sum += __shfl_xor(sum, off);
        aw[tid] = ex / sum;
    }
    __syncthreads();
    {
        float w0 = 0.f, w1 = 0.f;
        for (int s2 = 0; s2 < 64; ++s2) {
            float as = aw[s2];
            const float* eo = enc_out + ((size_t)b * 64 + s2) * 512;
            w0 = fmaf(as, eo[tid], w0);
            w1 = fmaf(as, eo[256 + tid], w1);
        }
        feat[b * 1024 + 256 + tid] = w0;
        feat[b * 1024 + 512 + tid] = w1;
    }
}

// ---------------------------------------------------------------------------
// Decoder GRU step.
__global__ __launch_bounds__(256) void dec_gru_kernel(
    const float* __restrict__ feat, const float* __restrict__ hin,
    const float* __restrict__ Wih, const float* __restrict__ Whh,
    const float* __restrict__ bih, const float* __restrict__ bhh,
    float* __restrict__ hout, float* __restrict__ feat_h)
{
    const int tid = threadIdx.x;
    const int dl = tid & 31, bsub = tid >> 5;
    const int d0 = (blockIdx.x & 7) * 32, b0 = (blockIdx.x >> 3) * 8;
    const int d = d0 + dl, b = b0 + bsub;

    __shared__ float rin[8][768];
    __shared__ float hsh[8][256];
    for (int i = tid; i < 2048; i += 256) {           // e -> rin[:,0:256]
        int bl = i >> 8, k = i & 255;
        rin[bl][k] = feat[(b0 + bl) * 1024 + 768 + k];
    }
    for (int i = tid; i < 4096; i += 256) {           // w -> rin[:,256:768]
        int bl = i >> 9, k = i & 511;
        rin[bl][256 + k] = feat[(b0 + bl) * 1024 + 256 + k];
    }
    for (int i = tid; i < 2048; i += 256) {
        int bl = i >> 8, k = i & 255;
        hsh[bl][k] = hin[(b0 + bl) * 256 + k];
    }
    __syncthreads();

    const float4* xv4 = (const float4*)rin[bsub];
    const float4* hv4 = (const float4*)hsh[bsub];
    const float4* Wr = (const float4*)(Wih + (size_t)d * 768);
    const float4* Wz = (const float4*)(Wih + (size_t)(256 + d) * 768);
    const float4* Wn = (const float4*)(Wih + (size_t)(512 + d) * 768);
    const float4* Ur = (const float4*)(Whh + (size_t)d * 256);
    const float4* Uz = (const float4*)(Whh + (size_t)(256 + d) * 256);
    const float4* Un = (const float4*)(Whh + (size_t)(512 + d) * 256);

    float rs = 0.f, zs = 0.f, nx = 0.f, nh = 0.f;
    for (int k = 0; k < 192; ++k) {
        float4 xv = xv4[k];
        rs += dot4(xv, Wr[k]);
        zs += dot4(xv, Wz[k]);
        nx += dot4(xv, Wn[k]);
    }
    for (int k = 0; k < 64; ++k) {
        float4 hv = hv4[k];
        rs += dot4(hv, Ur[k]);
        zs += dot4(hv, Uz[k]);
        nh += dot4(hv, Un[k]);
    }
    rs += bih[d] + bhh[d];
    zs += bih[256 + d] + bhh[256 + d];
    nx += bih[512 + d];
    nh += bhh[512 + d];

    float r = 1.0f / (1.0f + expf(-rs));
    float z = 1.0f / (1.0f + expf(-zs));
    float n = tanhf(nx + r * nh);
    float hprev = hsh[bsub][d];
    float hn = (1.0f - z) * n + z * hprev;

    hout[b * 256 + d] = hn;
    feat_h[b * 1024 + d] = hn;
}

// ---------------------------------------------------------------------------
// Argmax (first-max, matching jnp.argmax) + next-token embedding. float4 loads.
__global__ __launch_bounds__(256) void argmax_kernel(
    const float* __restrict__ logits, const float* __restrict__ table,
    int* __restrict__ tok, float* __restrict__ feat)
{
    const int b = blockIdx.x, tid = threadIdx.x;
    const float4* row4 = (const float4*)(logits + (long)b * 640000);
    float best = -3.402823466e38f;
    int bi = 0;
    for (int v4 = tid; v4 < 2500; v4 += 256) {
        float4 x = row4[v4];
        int base = v4 << 2;
        if (x.x > best) { best = x.x; bi = base; }
        if (x.y > best) { best = x.y; bi = base + 1; }
        if (x.z > best) { best = x.z; bi = base + 2; }
        if (x.w > best) { best = x.w; bi = base + 3; }
    }
    __shared__ float bv[256];
    __shared__ int bix[256];
    bv[tid] = best; bix[tid] = bi;
    __syncthreads();
    for (int s2 = 128; s2; s2 >>= 1) {
        if (tid < s2) {
            float o = bv[tid + s2]; int oi = bix[tid + s2];
            if (o > bv[tid] || (o == bv[tid] && oi < bix[tid])) { bv[tid] = o; bix[tid] = oi; }
        }
        __syncthreads();
    }
    int t0 = bix[0];
    if (tid == 0) tok[b] = t0;
    feat[b * 1024 + 768 + tid] = table[(size_t)t0 * 256 + tid];
}

// ---------------------------------------------------------------------------
__global__ void init_e_kernel(const float* __restrict__ table, float* __restrict__ feat) {
    feat[blockIdx.x * 1024 + 768 + threadIdx.x] = table[threadIdx.x];
}

// ---------------------------------------------------------------------------
// In-place log_softmax over each row of d_out (8192 x 10000).
__global__ __launch_bounds__(256) void logsoftmax_kernel(float* __restrict__ out) {
    const int row = blockIdx.x;
    float* p = out + (long)row * 10000;
    const int tid = threadIdx.x;
    __shared__ float red[256];

    if ((row & 63) == 0) {
        float lse = logf(expf(1.0f) + 9999.0f);
        for (int v = tid; v < 10000; v += 256) p[v] = (v == 0 ? 1.0f : 0.0f) - lse;
        return;
    }

    float vals[40];
    float m = -3.402823466e38f;
#pragma unroll
    for (int i = 0; i < 40; ++i) {
        int v = tid + (i << 8);
        vals[i] = (v < 10000) ? p[v] : -3.402823466e38f;
        m = fmaxf(m, vals[i]);
    }
    red[tid] = m; __syncthreads();
    for (int s2 = 128; s2; s2 >>= 1) { if (tid < s2) red[tid] = fmaxf(red[tid], red[tid + s2]); __syncthreads(); }
    m = red[0]; __syncthreads();

    float sum = 0.f;
#pragma unroll
    for (int i = 0; i < 40; ++i) {
        int v = tid + (i << 8);
        if (v < 10000) sum += expf(vals[i] - m);
    }
    red[tid] = sum; __syncthreads();
    for (int s2 = 128; s2; s2 >>= 1) { if (tid < s2) red[tid] += red[tid + s2]; __syncthreads(); }
    float lse = m + logf(red[0]);

#pragma unroll
    for (int i = 0; i < 40; ++i) {
        int v = tid + (i << 8);
        if (v < 10000) p[v] = vals[i] - lse;
    }
}

// ---------------------------------------------------------------------------
extern "C" void kernel_launch(void* const* d_in, const int* in_sizes, int n_in,
                              void* d_out, int out_size, void* d_ws, size_t ws_size,
                              hipStream_t stream)
{
    const int*   inp      = (const int*)d_in[0];
    const float* emb_tab  = (const float*)d_in[1];
    const float* eWih_f   = (const float*)d_in[2];
    const float* eWhh_f   = (const float*)d_in[3];
    const float* ebih_f   = (const float*)d_in[4];
    const float* ebhh_f   = (const float*)d_in[5];
    const float* eWih_b   = (const float*)d_in[6];
    const float* eWhh_b   = (const float*)d_in[7];
    const float* ebih_b   = (const float*)d_in[8];
    const float* ebhh_b   = (const float*)d_in[9];
    const float* fc_W     = (const float*)d_in[10];
    const float* fc_b     = (const float*)d_in[11];
    const float* attn_W   = (const float*)d_in[12];
    const float* attn_b   = (const float*)d_in[13];
    const float* dWih     = (const float*)d_in[14];
    const float* dWhh     = (const float*)d_in[15];
    const float* dbih     = (const float*)d_in[16];
    const float* dbhh     = (const float*)d_in[17];
    const float* out_W    = (const float*)d_in[18];
    const float* out_b    = (const float*)d_in[19];

    float* ws = (float*)d_ws;
    float* emb     = ws;                    // 2,097,152  (B*S*E)
    float* enc_out = emb + 2097152;         // 4,194,304  (B*S*512)
    float* enc_att = enc_out + 4194304;     // 2,097,152  (B*S*256)
    float* hf      = enc_att + 2097152;     // 2 * 32768
    float* hb      = hf + 65536;            // 2 * 32768
    float* hdec    = hb + 65536;            // 2 * 32768
    float* feat    = hdec + 65536;          // 131,072    (B*1024)
    int*   tok     = (int*)(feat + 131072); // 128
    float* out     = (float*)d_out;

    // ---- encoder ----
    embed_kernel<<<8192, 256, 0, stream>>>(inp, emb_tab, emb);
    hipMemsetAsync(hf, 0, 32768 * sizeof(float), stream);
    hipMemsetAsync(hb, 0, 32768 * sizeof(float), stream);
    for (int i = 0; i < 64; ++i) {
        const float* hinf = hf + (i & 1) * 32768;
        float* houtf = hf + ((i + 1) & 1) * 32768;
        const float* hinb = hb + (i & 1) * 32768;
        float* houtb = hb + ((i + 1) & 1) * 32768;
        enc_step_kernel<<<dim3(128, 2), 256, 0, stream>>>(
            emb, eWih_f, eWhh_f, ebih_f, ebhh_f, eWih_b, eWhh_b, ebih_b, ebhh_b,
            hinf, houtf, hinb, houtb, enc_out, i);
    }
    enc_fc_kernel<<<128, 256, 0, stream>>>(hf, hb, fc_W, fc_b, hdec);

    // enc_att[b,s,a] = enc_out @ attn_W[:,256:768].T + attn_b
    gemm2_kernel<<<dim3(4, 128), 256, 0, stream>>>(
        enc_out, 512, attn_W + 256, 768, attn_b, enc_att, 256, 256, 512);

    init_e_kernel<<<128, 256, 0, stream>>>(emb_tab, feat);

    // ---- decoder ----
    for (int t = 1; t < 64; ++t) {
        const float* hprev = hdec + ((t - 1) & 1) * 32768;
        float* hcur = hdec + (t & 1) * 32768;
        attn_kernel<<<128, 256, 0, stream>>>(hprev, attn_W, enc_att, enc_out, feat);
        dec_gru_kernel<<<128, 256, 0, stream>>>(feat, hprev, dWih, dWhh, dbih, dbhh, hcur, feat);
        gemm2_kernel<<<dim3(157, 2), 256, 0, stream>>>(
            feat, 1024, out_W, 1024, out_b, out + (long)t * 10000, 640000, 10000, 1024);
        if (t < 63)
            argmax_kernel<<<128, 256, 0, stream>>>(out + (long)t * 10000, emb_tab, tok, feat);
    }

    // ---- final log_softmax (also writes the t=0 one-hot rows) ----
    logsoftmax_kernel<<<8192, 256, 0, stream>>>(out);
}